// Round 2
// baseline (264.317 us; speedup 1.0000x reference)
//
#include <hip/hip_runtime.h>
#include <cstdint>

typedef __bf16 bf16;
typedef __bf16 bf16x8 __attribute__((ext_vector_type(8)));
typedef float f32x4 __attribute__((ext_vector_type(4)));

#define MFMA16(a, b, c) __builtin_amdgcn_mfma_f32_16x16x32_bf16((a), (b), (c), 0, 0, 0)
#define GLDS16(g, l)                                                         \
  __builtin_amdgcn_global_load_lds(                                          \
      (__attribute__((address_space(1))) void*)(g),                          \
      (__attribute__((address_space(3))) void*)(l), 16, 0, 0)

// ---- one prep kernel: 6 weight transposes + x/ctx/img casts (grid z=11) ----
__global__ void prep_all(const float* __restrict__ Wq, const float* __restrict__ Wo,
                         const float* __restrict__ Wk, const float* __restrict__ Wv,
                         const float* __restrict__ Wkip, const float* __restrict__ Wvip,
                         bf16* __restrict__ WqT, bf16* __restrict__ WoT,
                         bf16* __restrict__ WkT, bf16* __restrict__ WvT,
                         bf16* __restrict__ WkipT, bf16* __restrict__ WvipT,
                         const float* __restrict__ x, bf16* __restrict__ xb,
                         const float* __restrict__ ctx, bf16* __restrict__ ctxb,
                         const float* __restrict__ img, bf16* __restrict__ imgb) {
  const int z = blockIdx.z;
  const int tx = threadIdx.x, ty = threadIdx.y;
  if (z < 6) {
    const float* src = (z == 0) ? Wq : (z == 1) ? Wo : (z == 2) ? Wk
                      : (z == 3) ? Wv : (z == 4) ? Wkip : Wvip;
    bf16* dst = (z == 0) ? WqT : (z == 1) ? WoT : (z == 2) ? WkT
               : (z == 3) ? WvT : (z == 4) ? WkipT : WvipT;
    const int K = (z < 2) ? 1280 : 2048;
    const int N = 1280;
    __shared__ float t[32][33];
    const int bx = blockIdx.x * 32, by = blockIdx.y * 32;
    if (by >= K) return;
#pragma unroll
    for (int i = 0; i < 32; i += 8)
      t[ty + i][tx] = src[(long)(by + ty + i) * N + bx + tx];
    __syncthreads();
#pragma unroll
    for (int i = 0; i < 32; i += 8)
      dst[(long)(bx + ty + i) * K + by + tx] = (bf16)t[tx][ty + i];
    return;
  }
  const int tid = ty * 32 + tx;
  const int bid = blockIdx.y * 40 + blockIdx.x;  // 0..2559
  const float* s;
  bf16* d;
  long base;
  if (z < 10) {  // x: 4 slices x 2560 blocks x 2048 elems = 20971520 exact
    base = (((long)(z - 6) * 2560 + bid) * 256 + tid) * 8;
    s = x; d = xb;
  } else if (bid < 308) {  // ctx: 308*2048 = 630784 exact
    base = ((long)bid * 256 + tid) * 8;
    s = ctx; d = ctxb;
  } else if (bid < 372) {  // img: 64*2048 = 131072 exact
    base = ((long)(bid - 308) * 256 + tid) * 8;
    s = img; d = imgb;
  } else {
    return;
  }
  float4 a = *(const float4*)(s + base);
  float4 b = *(const float4*)(s + base + 4);
  bf16x8 o;
  o[0] = (bf16)a.x; o[1] = (bf16)a.y; o[2] = (bf16)a.z; o[3] = (bf16)a.w;
  o[4] = (bf16)b.x; o[5] = (bf16)b.y; o[6] = (bf16)b.z; o[7] = (bf16)b.w;
  *(bf16x8*)(d + base) = o;
}

// ============ 256x256 8-phase GEMM core: C = A[M,K] @ Bt[N,K]^T ============
// 512 thr = 8 waves (2M x 4N), per-wave output 128x64, BK=64 (K-tile).
// LDS 128 KB: A[2][256x64] + B[2][256x64], double-buffered per K-tile.
// Swizzle: LDS[row][c16] holds global col16 (c16 ^ (row&7)) — applied by
// pre-swizzling the per-lane GLOBAL source (gload_lds dest stays linear,
// rule #21) and XOR-ing on the ds_read side. Uniform 8-way bank spread.
// Per K-tile t (buffer b=t&1), 4 phases (quadrants of the wave's 128x64):
//   P0: read A(m0-3)+B(n0-1) [12xb128]; stage Ah1(t+1)->b^1; bar; lgkm0;
//       16 MFMA (rows0-3 x cols0-1); bar.
//   P1: read B(n2-3) [4]; stage Ah0(t+2)->b; ... MFMA rows0-3 x cols2-3.
//   P2: read A(m4-7) [8]; stage Bh0(t+2)->b; ... MFMA rows4-7 x cols2-3.
//   P3: stage Bh1(t+2)->b; bar; MFMA rows4-7 x cols0-1 (B regs from P0);
//       vmcnt(6) [3 half-tiles in flight -> t+1 fully landed]; bar.
// WAR: every stage slot is issued >=1 barrier after that slot's last reader
// (Ah0 last read P0, B last read P1, Ah1 last read P2).  RAW: vmcnt(6) at
// end-of-half + trailing barrier covers all of tile t+1 cross-wave.
// Tail: t+2>=NT -> skip stage; end-of-half vmcnt(0) when t+1 is last tile.
// Mlim guards C stores (small GEMMs reuse padless buffers; A-row overreads
// spill into the NEXT workspace buffer — read-only, garbage rows unused).
template <bool OUT_BF16, bool HAS_BIAS>
__device__ __forceinline__ void gemm256_core(const bf16* A, const bf16* Bt,
                                             void* Cp, const float* bias,
                                             int K, int N, int tm, int tn,
                                             int Mlim) {
  __shared__ bf16 Al[2][16384];
  __shared__ bf16 Bl[2][16384];
  const int tid = threadIdx.x;
  const int wave = tid >> 6, lane = tid & 63;
  const int g = lane >> 4, l16 = lane & 15;
  const int wr = wave >> 2, wc = wave & 3;

  // staging: wave w inst j writes LDS half_base + (w*2+j)*1024B linearly;
  // lane l -> row (w*2+j)*8 + (l>>3), col16 (l&7); source col pre-swizzled.
  const int srow = wave * 16 + (lane >> 3);
  const int scol = ((lane & 7) ^ ((lane >> 3) & 7)) * 8;
  const bf16* gA = A + (long)(tm + srow) * K + scol;
  const bf16* gB = Bt + (long)(tn + srow) * K + scol;
  const int ldst = wave * 1024;  // elements

#define STAGE_HALF(Lb_, gp_, b_, hh_, t_)                         \
  {                                                               \
    const bf16* s_ = (gp_) + (long)(hh_) * 128 * K + (t_) * 64;   \
    GLDS16(s_, &Lb_[b_][(hh_)*8192 + ldst]);                      \
    GLDS16(s_ + 8 * K, &Lb_[b_][(hh_)*8192 + ldst + 512]);        \
  }

  // compute-read: global col16 v at row r lives at LDS col16 v^(r&7); all
  // frag rows are (mult of 16)+l16 so r&7 == l16&7.
  const int cs0 = (g ^ (l16 & 7)) * 8;        // kslot 0
  const int cs1 = ((4 + g) ^ (l16 & 7)) * 8;  // kslot 1
  const int aB0 = (wr * 64 + l16) * 64;       // A rows group m0-3 (half 0)
  const int aB1 = aB0 + 8192;                 // A rows group m4-7 (half 1)
  const int bB = (wc * 64 + l16) * 64;

  f32x4 acc[8][4] = {};
  bf16x8 aF[4][2], bF[4][2];

  const int NT = K >> 6;  // K-tiles of 64 (20 or 32)

  // prologue: tile0 (4 half-tiles) + tile1 minus Ah1 (3 half-tiles)
  STAGE_HALF(Al, gA, 0, 0, 0);
  STAGE_HALF(Al, gA, 0, 1, 0);
  STAGE_HALF(Bl, gB, 0, 0, 0);
  STAGE_HALF(Bl, gB, 0, 1, 0);
  STAGE_HALF(Al, gA, 1, 0, 1);
  STAGE_HALF(Bl, gB, 1, 0, 1);
  STAGE_HALF(Bl, gB, 1, 1, 1);
  asm volatile("s_waitcnt vmcnt(6)" ::: "memory");  // 14 issued, oldest 8 = tile0
  asm volatile("s_barrier" ::: "memory");

  for (int t = 0; t < NT; ++t) {
    const int b = t & 1;
    // ---------------- P0 ----------------
#pragma unroll
    for (int mi = 0; mi < 4; ++mi) {
      aF[mi][0] = *(const bf16x8*)&Al[b][aB0 + mi * 1024 + cs0];
      aF[mi][1] = *(const bf16x8*)&Al[b][aB0 + mi * 1024 + cs1];
    }
#pragma unroll
    for (int nj = 0; nj < 2; ++nj) {
      bF[nj][0] = *(const bf16x8*)&Bl[b][bB + nj * 1024 + cs0];
      bF[nj][1] = *(const bf16x8*)&Bl[b][bB + nj * 1024 + cs1];
    }
    if (t + 1 < NT) STAGE_HALF(Al, gA, b ^ 1, 1, t + 1);
    asm volatile("s_barrier" ::: "memory");
    asm volatile("s_waitcnt lgkmcnt(0)" ::: "memory");
    __builtin_amdgcn_sched_barrier(0);
    __builtin_amdgcn_s_setprio(1);
#pragma unroll
    for (int mi = 0; mi < 4; ++mi)
#pragma unroll
      for (int nj = 0; nj < 2; ++nj) {
        acc[mi][nj] = MFMA16(aF[mi][0], bF[nj][0], acc[mi][nj]);
        acc[mi][nj] = MFMA16(aF[mi][1], bF[nj][1], acc[mi][nj]);
      }
    __builtin_amdgcn_s_setprio(0);
    asm volatile("s_barrier" ::: "memory");
    // ---------------- P1 ----------------
#pragma unroll
    for (int nj = 2; nj < 4; ++nj) {
      bF[nj][0] = *(const bf16x8*)&Bl[b][bB + nj * 1024 + cs0];
      bF[nj][1] = *(const bf16x8*)&Bl[b][bB + nj * 1024 + cs1];
    }
    if (t + 2 < NT) STAGE_HALF(Al, gA, b, 0, t + 2);
    asm volatile("s_barrier" ::: "memory");
    asm volatile("s_waitcnt lgkmcnt(0)" ::: "memory");
    __builtin_amdgcn_sched_barrier(0);
    __builtin_amdgcn_s_setprio(1);
#pragma unroll
    for (int mi = 0; mi < 4; ++mi)
#pragma unroll
      for (int nj = 2; nj < 4; ++nj) {
        acc[mi][nj] = MFMA16(aF[mi][0], bF[nj][0], acc[mi][nj]);
        acc[mi][nj] = MFMA16(aF[mi][1], bF[nj][1], acc[mi][nj]);
      }
    __builtin_amdgcn_s_setprio(0);
    asm volatile("s_barrier" ::: "memory");
    // ---------------- P2 ----------------
#pragma unroll
    for (int mi = 0; mi < 4; ++mi) {
      aF[mi][0] = *(const bf16x8*)&Al[b][aB1 + mi * 1024 + cs0];
      aF[mi][1] = *(const bf16x8*)&Al[b][aB1 + mi * 1024 + cs1];
    }
    if (t + 2 < NT) STAGE_HALF(Bl, gB, b, 0, t + 2);
    asm volatile("s_barrier" ::: "memory");
    asm volatile("s_waitcnt lgkmcnt(0)" ::: "memory");
    __builtin_amdgcn_sched_barrier(0);
    __builtin_amdgcn_s_setprio(1);
#pragma unroll
    for (int mi = 0; mi < 4; ++mi)
#pragma unroll
      for (int nj = 2; nj < 4; ++nj) {
        acc[4 + mi][nj] = MFMA16(aF[mi][0], bF[nj][0], acc[4 + mi][nj]);
        acc[4 + mi][nj] = MFMA16(aF[mi][1], bF[nj][1], acc[4 + mi][nj]);
      }
    __builtin_amdgcn_s_setprio(0);
    asm volatile("s_barrier" ::: "memory");
    // ---------------- P3 ----------------
    if (t + 2 < NT) STAGE_HALF(Bl, gB, b, 1, t + 2);
    asm volatile("s_barrier" ::: "memory");
    __builtin_amdgcn_sched_barrier(0);
    __builtin_amdgcn_s_setprio(1);
#pragma unroll
    for (int mi = 0; mi < 4; ++mi)
#pragma unroll
      for (int nj = 0; nj < 2; ++nj) {
        acc[4 + mi][nj] = MFMA16(aF[mi][0], bF[nj][0], acc[4 + mi][nj]);
        acc[4 + mi][nj] = MFMA16(aF[mi][1], bF[nj][1], acc[4 + mi][nj]);
      }
    __builtin_amdgcn_s_setprio(0);
    if (t + 2 < NT) {
      asm volatile("s_waitcnt vmcnt(6)" ::: "memory");
    } else if (t + 1 < NT) {
      asm volatile("s_waitcnt vmcnt(0)" ::: "memory");
    }
    asm volatile("s_barrier" ::: "memory");
  }
#undef STAGE_HALF

#pragma unroll
  for (int mi = 0; mi < 8; ++mi) {
    const int rb = (mi < 4) ? (wr * 64 + mi * 16) : (128 + wr * 64 + (mi - 4) * 16);
#pragma unroll
    for (int nj = 0; nj < 4; ++nj) {
      const int col = tn + wc * 64 + nj * 16 + l16;
      float bv = 0.f;
      if (HAS_BIAS) bv = bias[col];
#pragma unroll
      for (int r = 0; r < 4; ++r) {
        const long row = (long)tm + rb + g * 4 + r;
        if (row < Mlim) {
          float v = acc[mi][nj][r] + bv;
          if (OUT_BF16)
            ((bf16*)Cp)[row * N + col] = (bf16)v;
          else
            ((float*)Cp)[row * N + col] = v;
        }
      }
    }
  }
}

// ---- grid 350: 30 small-GEMM tiles FIRST (K=2048, longest), then Q-proj
// (320 tiles, XCD supertile: chunk q&7, 8 tm x 5 tn walked tn-fastest:
// per-XCD set = A panel 640KB + Wq 3.2MB ~ L2-resident). Small tiles use
// Mlim store-guard; A-row overreads land in the next workspace buffer. ----
__global__ __launch_bounds__(512, 2) void gemm_qproj_small(
    const bf16* __restrict__ xb, const bf16* __restrict__ WqT,
    bf16* __restrict__ qb, const bf16* __restrict__ ctxb,
    const bf16* __restrict__ imgb, const bf16* __restrict__ WkT,
    const bf16* __restrict__ WvT, const bf16* __restrict__ WkipT,
    const bf16* __restrict__ WvipT, bf16* __restrict__ kb,
    bf16* __restrict__ vb, bf16* __restrict__ ipkb, bf16* __restrict__ ipvb) {
  const int i = blockIdx.x;
  const bf16 *A, *Bt;
  bf16* C;
  int K, tm, tn, Mlim;
  if (i >= 30) {
    const int q = i - 30;      // 0..319
    const int local = q >> 3;  // 0..39
    A = xb; Bt = WqT; C = qb; K = 1280; Mlim = 1 << 30;
    tm = ((q & 7) * 8 + local / 5) * 256;
    tn = (local % 5) * 256;
  } else {
    // 0..9 K-proj (2Mx5N), 10..19 V-proj, 20..24 ipK, 25..29 ipV
    int z, bx, by;
    if (i < 20) {
      z = i / 10;
      const int r = i % 10;
      bx = r / 5; by = r % 5;
    } else {
      z = 2 + (i - 20) / 5;
      bx = 0; by = (i - 20) % 5;
    }
    A = (z < 2) ? ctxb : imgb;
    Bt = (z == 0) ? WkT : (z == 1) ? WvT : (z == 2) ? WkipT : WvipT;
    C = (z == 0) ? kb : (z == 1) ? vb : (z == 2) ? ipkb : ipvb;
    K = 2048;
    tm = bx * 256;
    tn = by * 256;
    Mlim = (z < 2) ? 384 : 128;  // buffer row counts (valid rows 308 / 64)
  }
  gemm256_core<true, false>(A, Bt, C, nullptr, K, 1280, tm, tn, Mlim);
}

// ---- out-proj, grid 320, same supertile map ----
__global__ __launch_bounds__(512, 2) void gemm_f32out_bias(
    const bf16* __restrict__ A, const bf16* __restrict__ Bt,
    float* __restrict__ C, const float* __restrict__ bias, int K, int N) {
  const int i = blockIdx.x;
  const int local = i >> 3;
  const int tm = ((i & 7) * 8 + local / 5) * 256;
  const int tn = (local % 5) * 256;
  gemm256_core<false, true>(A, Bt, C, bias, K, N, tm, tn, 1 << 30);
}

// ---------------- fused dual cross-attention (unchanged) ----------------
__global__ __launch_bounds__(256) void attention_kernel(
    const bf16* __restrict__ q, const bf16* __restrict__ k,
    const bf16* __restrict__ v, const bf16* __restrict__ ipk,
    const bf16* __restrict__ ipv, bf16* __restrict__ out) {
  __shared__ bf16 Kl[96 * 64];
  __shared__ bf16 Vt[64 * 104];
  __shared__ bf16 Pl[4][16 * 104];

  const int b = blockIdx.z, h = blockIdx.y, qblk = blockIdx.x;
  const int tid = threadIdx.x;

  {
    uint32_t* vz = (uint32_t*)Vt;
    for (int i = tid; i < 64 * 104 / 2; i += 256) vz[i] = 0;
  }
  __syncthreads();

  for (int c = tid; c < 77 * 8; c += 256) {
    const int row = c >> 3, d0 = (c & 7) * 8;
    const long src = (long)(b * 77 + row) * 1280 + h * 64 + d0;
    bf16x8 kk = *(const bf16x8*)&k[src];
    *(bf16x8*)&Kl[row * 64 + (d0 ^ ((row & 7) << 3))] = kk;
    bf16x8 vv = *(const bf16x8*)&v[src];
#pragma unroll
    for (int i2 = 0; i2 < 8; i2++) Vt[(d0 + i2) * 104 + row] = vv[i2];
  }
  if (tid < 16 * 8) {
    const int r = tid >> 3, d0 = (tid & 7) * 8;
    const int row = 80 + r;
    const long src = (long)(b * 16 + r) * 1280 + h * 64 + d0;
    bf16x8 kk = *(const bf16x8*)&ipk[src];
    *(bf16x8*)&Kl[row * 64 + (d0 ^ ((row & 7) << 3))] = kk;
    bf16x8 vv = *(const bf16x8*)&ipv[src];
#pragma unroll
    for (int i2 = 0; i2 < 8; i2++) Vt[(d0 + i2) * 104 + row] = vv[i2];
  }
  __syncthreads();

  const int wave = tid >> 6, lane = tid & 63;
  const int g = lane >> 4, l16 = lane & 15;
  const float sc = 0.125f * 1.44269504f;  // 1/sqrt(64) * log2(e)

  for (int it = 0; it < 2; it++) {
    const long qrow = (long)b * 4096 + qblk * 128 + wave * 32 + it * 16;
    bf16x8 qf[2];
#pragma unroll
    for (int ks = 0; ks < 2; ks++)
      qf[ks] = *(const bf16x8*)&q[(qrow + l16) * 1280 + h * 64 + ks * 32 + g * 8];

    f32x4 lt[6];
#pragma unroll
    for (int t = 0; t < 6; t++) {
      f32x4 a = {0.f, 0.f, 0.f, 0.f};
#pragma unroll
      for (int ks = 0; ks < 2; ks++) {
        const int row = t * 16 + l16;
        const int d = (ks * 32 + g * 8) ^ ((row & 7) << 3);
        bf16x8 kb8 = *(const bf16x8*)&Kl[row * 64 + d];
        a = MFMA16(qf[ks], kb8, a);
      }
      lt[t] = a;
    }

    float p[6][4];
#pragma unroll
    for (int r = 0; r < 4; r++) {
      float lv[5], m = -3e38f;
#pragma unroll
      for (int t = 0; t < 5; t++) {
        const int kv = t * 16 + l16;
        lv[t] = (kv < 77) ? lt[t][r] * sc : -3e38f;
        m = fmaxf(m, lv[t]);
      }
      for (int msk = 1; msk < 16; msk <<= 1) m = fmaxf(m, __shfl_xor(m, msk, 16));
      float s = 0.f;
#pragma unroll
      for (int t = 0; t < 5; t++) {
        const float pp = exp2f(lv[t] - m);
        p[t][r] = pp;
        s += pp;
      }
      for (int msk = 1; msk < 16; msk <<= 1) s += __shfl_xor(s, msk, 16);
      const float inv = 1.f / s;
#pragma unroll
      for (int t = 0; t < 5; t++) p[t][r] *= inv;
      const float l5 = lt[5][r] * sc;
      float m2 = l5;
      for (int msk = 1; msk < 16; msk <<= 1) m2 = fmaxf(m2, __shfl_xor(m2, msk, 16));
      const float p5 = exp2f(l5 - m2);
      float s2 = p5;
      for (int msk = 1; msk < 16; msk <<= 1) s2 += __shfl_xor(s2, msk, 16);
      p[5][r] = p5 / s2;
    }

#pragma unroll
    for (int t = 0; t < 6; t++)
#pragma unroll
      for (int r = 0; r < 4; r++)
        Pl[wave][(g * 4 + r) * 104 + t * 16 + l16] = (bf16)p[t][r];
    __syncthreads();

    bf16x8 paf[3];
#pragma unroll
    for (int ks = 0; ks < 3; ks++)
      paf[ks] = *(const bf16x8*)&Pl[wave][l16 * 104 + ks * 32 + g * 8];
#pragma unroll
    for (int n = 0; n < 4; n++) {
      f32x4 o = {0.f, 0.f, 0.f, 0.f};
#pragma unroll
      for (int ks = 0; ks < 3; ks++) {
        bf16x8 vbf = *(const bf16x8*)&Vt[(n * 16 + l16) * 104 + ks * 32 + g * 8];
        o = MFMA16(paf[ks], vbf, o);
      }
#pragma unroll
      for (int r = 0; r < 4; r++)
        out[(qrow + g * 4 + r) * 1280 + h * 64 + n * 16 + l16] = (bf16)o[r];
    }
    __syncthreads();
  }
}

// ---------------- host launch ----------------
extern "C" void kernel_launch(void* const* d_in, const int* in_sizes, int n_in,
                              void* d_out, int out_size, void* d_ws,
                              size_t ws_size, hipStream_t stream) {
  const float* x = (const float*)d_in[0];
  const float* ctx = (const float*)d_in[1];
  const float* img = (const float*)d_in[2];
  const float* Wq = (const float*)d_in[3];
  const float* Wk = (const float*)d_in[4];
  const float* Wv = (const float*)d_in[5];
  const float* Wkip = (const float*)d_in[6];
  const float* Wvip = (const float*)d_in[7];
  const float* Wo = (const float*)d_in[8];
  const float* bo = (const float*)d_in[9];
  float* out = (float*)d_out;

  bf16* ws = (bf16*)d_ws;
  size_t o = 0;
  auto alloc = [&](size_t n) { bf16* p = ws + o; o += n; return p; };
  bf16* xattn = alloc(16384L * 1280);  // x_bf16, later reused for attn output
  bf16* qb    = alloc(16384L * 1280);
  bf16* WqT   = alloc(1280L * 1280);
  bf16* WoT   = alloc(1280L * 1280);
  bf16* WkT   = alloc(1280L * 2048);
  bf16* WvT   = alloc(1280L * 2048);
  bf16* WkipT = alloc(1280L * 2048);
  bf16* WvipT = alloc(1280L * 2048);
  bf16* ctxb  = alloc(384L * 2048);   // 308 valid rows; 256-tile overread -> imgb
  bf16* imgb  = alloc(128L * 2048);   // 64 valid rows; overread -> kb
  bf16* kb    = alloc(384L * 1280);   // stores guarded by Mlim=384
  bf16* vb    = alloc(384L * 1280);
  bf16* ipkb  = alloc(128L * 1280);   // stores guarded by Mlim=128
  bf16* ipvb  = alloc(128L * 1280);

  // all prep (6 transposes + 3 casts) in one launch
  prep_all<<<dim3(40, 64, 11), dim3(32, 8), 0, stream>>>(
      Wq, Wo, Wk, Wv, Wkip, Wvip, WqT, WoT, WkT, WvT, WkipT, WvipT, x, xattn,
      ctx, ctxb, img, imgb);

  // small projections (longest blocks) first, then Q-proj supertile
  gemm_qproj_small<<<350, 512, 0, stream>>>(xattn, WqT, qb, ctxb, imgb, WkT,
                                            WvT, WkipT, WvipT, kb, vb, ipkb,
                                            ipvb);

  // fused dual attention -> xattn (reuses x_bf16 buffer)
  attention_kernel<<<dim3(32, 20, 4), 256, 0, stream>>>(qb, kb, vb, ipkb, ipvb,
                                                        xattn);

  // output projection + bias: out = attn @ Wo + bo (f32 out)
  gemm_f32out_bias<<<320, 512, 0, stream>>>(xattn, WoT, out, bo, 1280, 1280);
}